// Round 9
// baseline (1170.822 us; speedup 1.0000x reference)
//
#include <hip/hip_runtime.h>
#include <cstddef>

#define NN  100000
#define NE  600000
#define NG  4096
#define DIN 73
#define DE  101
#define DD  128
#define DD2 256
#define NP  100096   // NN padded to 64-row tiles
#define EP  600064   // NE padded to 128-row tiles (4688 tiles)

typedef unsigned int uint;
typedef unsigned short ushort;
typedef __attribute__((ext_vector_type(8))) short bf16x8;
typedef __attribute__((ext_vector_type(4))) float f32x4;

__device__ __forceinline__ void fadd_atomic(float* p, float v) { unsafeAtomicAdd(p, v); }

__device__ __forceinline__ ushort f2bf(float f) {   // RNE f32->bf16
    uint u = __float_as_uint(f);
    uint r = (u + 0x7fffu + ((u >> 16) & 1u)) >> 16;
    return (ushort)r;
}
__device__ __forceinline__ float bf2f(ushort u) { return __uint_as_float(((uint)u) << 16); }

// f32x8 -> bf16x8 fragment (for mlp1 reading f32 z)
__device__ __forceinline__ bf16x8 ld_zfrag(const float* __restrict__ p) {
    const float4 f0 = *(const float4*)p;
    const float4 f1 = *(const float4*)(p + 4);
    bf16x8 r;
    r[0] = (short)f2bf(f0.x); r[1] = (short)f2bf(f0.y);
    r[2] = (short)f2bf(f0.z); r[3] = (short)f2bf(f0.w);
    r[4] = (short)f2bf(f1.x); r[5] = (short)f2bf(f1.y);
    r[6] = (short)f2bf(f1.z); r[7] = (short)f2bf(f1.w);
    return r;
}

// ---------------- CSR build (once per call) ---------------------------------

__global__ void hist_kernel(const int* __restrict__ dst, int* __restrict__ deg) {
    int e = blockIdx.x * blockDim.x + threadIdx.x;
    if (e < NE) atomicAdd(&deg[dst[e]], 1);
}

__global__ __launch_bounds__(256) void scan_chunk_kernel(
    const int* __restrict__ deg, int* __restrict__ offs, int* __restrict__ csums)
{
    const int b = blockIdx.x, t = threadIdx.x;
    const int base = b * 1024 + t * 4;
    int v[4];
    #pragma unroll
    for (int i = 0; i < 4; ++i) v[i] = (base + i < NN) ? deg[base + i] : 0;
    int tsum = v[0] + v[1] + v[2] + v[3];
    const int lane = t & 63, w = t >> 6;
    int x = tsum;
    #pragma unroll
    for (int d = 1; d < 64; d <<= 1) {
        int y = __shfl_up(x, d, 64);
        if (lane >= d) x += y;
    }
    __shared__ int wsum[4];
    if (lane == 63) wsum[w] = x;
    __syncthreads();
    int woff = 0;
    for (int i = 0; i < w; ++i) woff += wsum[i];
    int run = woff + x - tsum;
    #pragma unroll
    for (int i = 0; i < 4; ++i) {
        if (base + i < NN) offs[base + i] = run;
        run += v[i];
    }
    if (t == 255) csums[b] = woff + x;
}

__global__ void scan_tops_kernel(int* __restrict__ csums, int* __restrict__ offs, int nchunks) {
    if (threadIdx.x == 0 && blockIdx.x == 0) {
        int run = 0;
        for (int i = 0; i < nchunks; ++i) { int c = csums[i]; csums[i] = run; run += c; }
        offs[NN] = run;
    }
}

__global__ void scan_add_kernel(int* __restrict__ offs, const int* __restrict__ csums) {
    int i = blockIdx.x * blockDim.x + threadIdx.x;
    if (i < NN) offs[i] += csums[i >> 10];
}

// builds eperm (edge -> csr position), srcp and dstp (csr-ordered src/dst)
__global__ void scatter_kernel(const int* __restrict__ dst, const int* __restrict__ src,
                               const int* __restrict__ offs, int* __restrict__ cursor,
                               int* __restrict__ eperm, int* __restrict__ srcp,
                               int* __restrict__ dstp)
{
    int e = blockIdx.x * blockDim.x + threadIdx.x;
    if (e >= NE) return;
    int d = dst[e];
    int pos = offs[d] + atomicAdd(&cursor[d], 1);
    eperm[e] = pos;
    srcp[pos] = src[e];
    dstp[pos] = d;
}

__global__ void gstart_kernel(const int* __restrict__ batch, int* __restrict__ gstart) {
    int n = blockIdx.x * blockDim.x + threadIdx.x;
    if (n > NN) return;
    if (n == NN) {
        for (int g = batch[NN - 1] + 1; g <= NG; ++g) gstart[g] = NN;
        return;
    }
    int b = batch[n];
    int pb = (n == 0) ? -1 : batch[n - 1];
    for (int g = pb + 1; g <= b; ++g) gstart[g] = n;
}

// ---------------- conversions ----------------------------------------------

// ea f32 [E,101] -> bf16 [EP,128] in CSR order; col 101 = 1.0 (bias slot)
__global__ __launch_bounds__(256) void cvt_ea_kernel(const float* __restrict__ ea,
                                                     const int* __restrict__ eperm,
                                                     ushort* __restrict__ eabc)
{
    const int t = threadIdx.x;
    const int r = blockIdx.x * 8 + (t >> 5);
    if (r >= NE) return;
    const int pos = eperm[r];
    const int c = (t & 31) * 4;
    ushort4 o;
    #pragma unroll
    for (int i = 0; i < 4; ++i) {
        const int col = c + i;
        float v = (col < DE) ? ea[(size_t)r * DE + col] : ((col == DE) ? 1.0f : 0.0f);
        ((ushort*)&o)[i] = f2bf(v);
    }
    *(ushort4*)&eabc[(size_t)pos * 128 + c] = o;
}

// in f32 [Kin,Nn] -> out bf16 [Nn][Kp] transposed; row Kin = bias (if given), rest 0
__global__ void cvt_wt_kernel(const float* __restrict__ in, ushort* __restrict__ out,
                              int Kin, int Nn, int Kp, const float* __restrict__ bias)
{
    const int n = blockIdx.x;
    for (int k = threadIdx.x; k < Kp; k += blockDim.x) {
        float v = 0.0f;
        if (k < Kin) v = in[(size_t)k * Nn + n];
        else if (k == Kin && bias) v = bias[n];
        out[(size_t)n * Kp + k] = f2bf(v);
    }
}

// ---------------- fused edge GEMM + segment-sum aggregation ------------------
// e = eabc@We(+be via K-slot); val = relu(e + h[srcp]); zf[dst] += segment sums.
// CSR rows contiguous per node -> interior segments (not touching a 64-row-half
// boundary) are exclusively owned: plain store of h+sum. Only the 2 boundary
// segments per half need atomics (12.7M -> ~2.6M atomics per layer).
__global__ __launch_bounds__(256, 2) void edge_agg_kernel(
    const ushort* __restrict__ eab, const ushort* __restrict__ Wt,
    const int* __restrict__ srcp, const int* __restrict__ dstp,
    const ushort* __restrict__ hb, float* __restrict__ zf)
{
    __shared__ ushort vals[128 * 128];   // [row][col], col XOR-swizzled by row
    __shared__ int nd[128];              // dst node per tile row
    const int tid = threadIdx.x;
    const int wid = tid >> 6;
    const int msub = wid >> 1, nsl = wid & 1;
    const int lane = tid & 63, l15 = lane & 15, grp = lane >> 4;
    const int n0 = nsl * 64;

    bf16x8 A[4][4];
    #pragma unroll
    for (int nf = 0; nf < 4; ++nf)
        #pragma unroll
        for (int kk = 0; kk < 4; ++kk)
            A[nf][kk] = *(const bf16x8*)(Wt + (size_t)(n0 + nf * 16 + l15) * 128 + kk * 32 + grp * 8);

    const int rcol = tid & 127;   // reduce-phase column
    const int rh   = tid >> 7;    // reduce-phase row half (0/1)

    const int ntiles = EP / 128;  // 4688
    for (int t = blockIdx.x; t < ntiles; t += gridDim.x) {
        const int r0 = t * 128;
        const int m0 = r0 + msub * 64;
        __syncthreads();          // previous tile's reduce done before overwriting LDS
        if (tid < 128) {
            const int rr = r0 + tid;
            nd[tid] = (rr < NE) ? dstp[rr] : NN;
        }
        // issue h-gather early (hides under MFMA)
        int sp[4];
        #pragma unroll
        for (int mf = 0; mf < 4; ++mf) {
            const int rr = m0 + mf * 16 + l15;
            sp[mf] = (rr < NE) ? srcp[rr] : 0;
        }
        ushort4 hv[4][4];
        #pragma unroll
        for (int mf = 0; mf < 4; ++mf)
            #pragma unroll
            for (int nf = 0; nf < 4; ++nf)
                hv[mf][nf] = *(const ushort4*)&hb[(size_t)sp[mf] * 128 + n0 + nf * 16 + grp * 4];
        // GEMM
        f32x4 acc[4][4];
        #pragma unroll
        for (int i = 0; i < 4; ++i)
            #pragma unroll
            for (int j = 0; j < 4; ++j) acc[i][j] = (f32x4){0.f, 0.f, 0.f, 0.f};
        #pragma unroll
        for (int kk = 0; kk < 4; ++kk) {
            bf16x8 b[4];
            #pragma unroll
            for (int mf = 0; mf < 4; ++mf)
                b[mf] = *(const bf16x8*)(eab + (size_t)(m0 + mf * 16 + l15) * 128 + kk * 32 + grp * 8);
            #pragma unroll
            for (int mf = 0; mf < 4; ++mf)
                #pragma unroll
                for (int nf = 0; nf < 4; ++nf)
                    acc[mf][nf] = __builtin_amdgcn_mfma_f32_16x16x32_bf16(A[nf][kk], b[mf], acc[mf][nf], 0, 0, 0);
        }
        // relu(e + h) -> LDS (swizzled: ushort-index col ^ ((row&7)<<3))
        #pragma unroll
        for (int mf = 0; mf < 4; ++mf) {
            const int row = msub * 64 + mf * 16 + l15;
            const int sw = (row & 7) << 3;
            #pragma unroll
            for (int nf = 0; nf < 4; ++nf) {
                const int col = n0 + nf * 16 + grp * 4;
                ushort4 o;
                o.x = f2bf(fmaxf(acc[mf][nf][0] + bf2f(hv[mf][nf].x), 0.f));
                o.y = f2bf(fmaxf(acc[mf][nf][1] + bf2f(hv[mf][nf].y), 0.f));
                o.z = f2bf(fmaxf(acc[mf][nf][2] + bf2f(hv[mf][nf].z), 0.f));
                o.w = f2bf(fmaxf(acc[mf][nf][3] + bf2f(hv[mf][nf].w), 0.f));
                *(ushort4*)&vals[row * 128 + (col ^ sw)] = o;
            }
        }
        __syncthreads();
        // serial segment reduce; first/last segments of the half -> atomic,
        // interior segments (exclusively owned) -> plain store of h + sum
        const int rstart = rh * 64;
        float accs = 0.f;
        int cur = nd[rstart];
        bool first = true;
        for (int r = rstart; r < rstart + 64; ++r) {
            const int node = nd[r];
            const float v = bf2f(vals[r * 128 + (rcol ^ ((r & 7) << 3))]);
            if (node != cur) {
                if (cur < NN) {
                    if (first) fadd_atomic(&zf[(size_t)cur * 128 + rcol], accs);
                    else zf[(size_t)cur * 128 + rcol] =
                             bf2f(hb[(size_t)cur * 128 + rcol]) + accs;
                }
                accs = 0.f; cur = node; first = false;
            }
            accs += v;
        }
        if (cur < NN) fadd_atomic(&zf[(size_t)cur * 128 + rcol], accs);
    }
}

// zf = f32(hb) for rows < NN, 0 for padded rows
__global__ void zinit_kernel(const ushort* __restrict__ hb, float* __restrict__ zf) {
    int i = blockIdx.x * blockDim.x + threadIdx.x;
    const int stride = gridDim.x * blockDim.x;
    for (; i < NP * 32; i += stride) {
        const int n = i >> 5;
        float4 o;
        if (n < NN) {
            ushort4 u = *(const ushort4*)&hb[(size_t)i * 4];
            o.x = bf2f(u.x); o.y = bf2f(u.y); o.z = bf2f(u.z); o.w = bf2f(u.w);
        } else {
            o.x = 0.f; o.y = 0.f; o.z = 0.f; o.w = 0.f;
        }
        *(float4*)&zf[(size_t)i * 4] = o;
    }
}

// ---------------- weight-stationary MFMA GEMMs ------------------------------

// mlp1: y1 = z@W1 + b1 -> bf16 [NP,256]; z is f32, converted in-register
__global__ __launch_bounds__(256, 2) void mlp1_gemm_kernel(
    const float* __restrict__ z, const ushort* __restrict__ Wt,
    const float* __restrict__ bias, ushort* __restrict__ y)
{
    const int n0 = (threadIdx.x >> 6) * 64;
    const int lane = threadIdx.x & 63, l15 = lane & 15, grp = lane >> 4;
    bf16x8 A[4][4];
    #pragma unroll
    for (int nf = 0; nf < 4; ++nf)
        #pragma unroll
        for (int kk = 0; kk < 4; ++kk)
            A[nf][kk] = *(const bf16x8*)(Wt + (size_t)(n0 + nf * 16 + l15) * 128 + kk * 32 + grp * 8);
    float4 bv[4];
    #pragma unroll
    for (int nf = 0; nf < 4; ++nf) bv[nf] = *(const float4*)&bias[n0 + nf * 16 + grp * 4];

    const int ntiles = NP / 64;   // 1564
    for (int t = blockIdx.x; t < ntiles; t += gridDim.x) {
        const int m0 = t * 64;
        f32x4 acc[4][4];
        #pragma unroll
        for (int i = 0; i < 4; ++i)
            #pragma unroll
            for (int j = 0; j < 4; ++j) acc[i][j] = (f32x4){0.f, 0.f, 0.f, 0.f};
        #pragma unroll
        for (int kk = 0; kk < 4; ++kk) {
            bf16x8 b[4];
            #pragma unroll
            for (int mf = 0; mf < 4; ++mf)
                b[mf] = ld_zfrag(z + (size_t)(m0 + mf * 16 + l15) * 128 + kk * 32 + grp * 8);
            #pragma unroll
            for (int mf = 0; mf < 4; ++mf)
                #pragma unroll
                for (int nf = 0; nf < 4; ++nf)
                    acc[mf][nf] = __builtin_amdgcn_mfma_f32_16x16x32_bf16(A[nf][kk], b[mf], acc[mf][nf], 0, 0, 0);
        }
        #pragma unroll
        for (int mf = 0; mf < 4; ++mf) {
            ushort* rp = &y[(size_t)(m0 + mf * 16 + l15) * 256 + n0];
            #pragma unroll
            for (int nf = 0; nf < 4; ++nf) {
                ushort4 o;
                o.x = f2bf(acc[mf][nf][0] + bv[nf].x);
                o.y = f2bf(acc[mf][nf][1] + bv[nf].y);
                o.z = f2bf(acc[mf][nf][2] + bv[nf].z);
                o.w = f2bf(acc[mf][nf][3] + bv[nf].w);
                *(ushort4*)&rp[nf * 16 + grp * 4] = o;
            }
        }
    }
}

// mlp2: y2 = relu(bn1(y1))@W2 + b2 -> bf16 [NP,128]; bn1+relu fused into B-load
// (bitwise identical to the separate bnrelu pass: f32 apply, round to bf16)
__global__ __launch_bounds__(256, 2) void mlp2_gemm_kernel(
    const ushort* __restrict__ y1, const float* __restrict__ a1f, const float* __restrict__ c1f,
    const ushort* __restrict__ Wt, const float* __restrict__ bias, ushort* __restrict__ y2)
{
    const int wid = threadIdx.x >> 6;
    const int msub = wid >> 1, nsl = wid & 1;
    const int lane = threadIdx.x & 63, l15 = lane & 15, grp = lane >> 4;
    const int n0 = nsl * 64;
    bf16x8 A[4][8];
    #pragma unroll
    for (int nf = 0; nf < 4; ++nf)
        #pragma unroll
        for (int kk = 0; kk < 8; ++kk)
            A[nf][kk] = *(const bf16x8*)(Wt + (size_t)(n0 + nf * 16 + l15) * 256 + kk * 32 + grp * 8);
    float4 bv[4];
    #pragma unroll
    for (int nf = 0; nf < 4; ++nf) bv[nf] = *(const float4*)&bias[n0 + nf * 16 + grp * 4];

    const int ntiles = NP / 128;   // 782
    for (int t = blockIdx.x; t < ntiles; t += gridDim.x) {
        const int m0 = t * 128 + msub * 64;
        f32x4 acc[4][4];
        #pragma unroll
        for (int i = 0; i < 4; ++i)
            #pragma unroll
            for (int j = 0; j < 4; ++j) acc[i][j] = (f32x4){0.f, 0.f, 0.f, 0.f};
        #pragma unroll
        for (int kk = 0; kk < 8; ++kk) {
            const int kb = kk * 32 + grp * 8;
            const float4 av0 = *(const float4*)&a1f[kb];
            const float4 av1 = *(const float4*)&a1f[kb + 4];
            const float4 cv0 = *(const float4*)&c1f[kb];
            const float4 cv1 = *(const float4*)&c1f[kb + 4];
            const float aa[8] = {av0.x, av0.y, av0.z, av0.w, av1.x, av1.y, av1.z, av1.w};
            const float cc[8] = {cv0.x, cv0.y, cv0.z, cv0.w, cv1.x, cv1.y, cv1.z, cv1.w};
            bf16x8 b[4];
            #pragma unroll
            for (int mf = 0; mf < 4; ++mf) {
                bf16x8 raw = *(const bf16x8*)(y1 + (size_t)(m0 + mf * 16 + l15) * 256 + kb);
                bf16x8 tb;
                #pragma unroll
                for (int j = 0; j < 8; ++j) {
                    float f = bf2f((ushort)raw[j]);
                    f = fmaxf(fmaf(f, aa[j], cc[j]), 0.f);
                    tb[j] = (short)f2bf(f);
                }
                b[mf] = tb;
            }
            #pragma unroll
            for (int mf = 0; mf < 4; ++mf)
                #pragma unroll
                for (int nf = 0; nf < 4; ++nf)
                    acc[mf][nf] = __builtin_amdgcn_mfma_f32_16x16x32_bf16(A[nf][kk], b[mf], acc[mf][nf], 0, 0, 0);
        }
        #pragma unroll
        for (int mf = 0; mf < 4; ++mf) {
            ushort* rp = &y2[(size_t)(m0 + mf * 16 + l15) * 128 + n0];
            #pragma unroll
            for (int nf = 0; nf < 4; ++nf) {
                ushort4 o;
                o.x = f2bf(acc[mf][nf][0] + bv[nf].x);
                o.y = f2bf(acc[mf][nf][1] + bv[nf].y);
                o.z = f2bf(acc[mf][nf][2] + bv[nf].z);
                o.w = f2bf(acc[mf][nf][3] + bv[nf].w);
                *(ushort4*)&rp[nf * 16 + grp * 4] = o;
            }
        }
    }
}

// ---------------- elementwise / stats kernels --------------------------------

// h = bf16(x @ W_emb + b_emb)  (runs once)
__global__ __launch_bounds__(128) void embed_kernel(
    const float* __restrict__ x, const float* __restrict__ W,
    const float* __restrict__ b, ushort* __restrict__ hb)
{
    __shared__ float xs[4][DIN];
    const int n0 = blockIdx.x * 4;
    const int d  = threadIdx.x;
    for (int idx = d; idx < 4 * DIN; idx += 128) {
        int r = idx / DIN, c = idx - r * DIN;
        xs[r][c] = x[(size_t)n0 * DIN + idx];
    }
    __syncthreads();
    float bb = b[d];
    float a0 = bb, a1 = bb, a2 = bb, a3 = bb;
    for (int k = 0; k < DIN; ++k) {
        float w = W[k * DD + d];
        a0 = fmaf(xs[0][k], w, a0);
        a1 = fmaf(xs[1][k], w, a1);
        a2 = fmaf(xs[2][k], w, a2);
        a3 = fmaf(xs[3][k], w, a3);
    }
    hb[(size_t)(n0 + 0) * DD + d] = f2bf(a0);
    hb[(size_t)(n0 + 1) * DD + d] = f2bf(a1);
    hb[(size_t)(n0 + 2) * DD + d] = f2bf(a2);
    hb[(size_t)(n0 + 3) * DD + d] = f2bf(a3);
}

// column sums/sumsq of bf16 [*,256], rows < NN
__global__ __launch_bounds__(256) void colstats256_kernel(
    const ushort* __restrict__ y, float* __restrict__ s, float* __restrict__ q)
{
    const int t = threadIdx.x;
    const int cs = (t & 63) * 4, rg = t >> 6;
    const int r0 = blockIdx.x * 256;
    float ps0 = 0, ps1 = 0, ps2 = 0, ps3 = 0, pq0 = 0, pq1 = 0, pq2 = 0, pq3 = 0;
    for (int i = rg; i < 256; i += 4) {
        const int r = r0 + i;
        if (r >= NN) break;
        ushort4 u = *(const ushort4*)&y[(size_t)r * 256 + cs];
        float f0 = bf2f(u.x), f1 = bf2f(u.y), f2v = bf2f(u.z), f3 = bf2f(u.w);
        ps0 += f0; pq0 += f0 * f0;
        ps1 += f1; pq1 += f1 * f1;
        ps2 += f2v; pq2 += f2v * f2v;
        ps3 += f3; pq3 += f3 * f3;
    }
    __shared__ float SS[4][256], SQ[4][256];
    SS[rg][cs + 0] = ps0; SS[rg][cs + 1] = ps1; SS[rg][cs + 2] = ps2; SS[rg][cs + 3] = ps3;
    SQ[rg][cs + 0] = pq0; SQ[rg][cs + 1] = pq1; SQ[rg][cs + 2] = pq2; SQ[rg][cs + 3] = pq3;
    __syncthreads();
    if (rg == 0) {
        #pragma unroll
        for (int j = 0; j < 4; ++j) {
            const int c = cs + j;
            fadd_atomic(&s[c], SS[0][c] + SS[1][c] + SS[2][c] + SS[3][c]);
            fadd_atomic(&q[c], SQ[0][c] + SQ[1][c] + SQ[2][c] + SQ[3][c]);
        }
    }
}

// column sums/sumsq of bf16 [*,128], rows < NN
__global__ __launch_bounds__(256) void colstats128b_kernel(
    const ushort* __restrict__ y, float* __restrict__ s, float* __restrict__ q)
{
    const int t = threadIdx.x;
    const int cs = (t & 31) * 4, rg = t >> 5;
    const int r0 = blockIdx.x * 256;
    float ps0 = 0, ps1 = 0, ps2 = 0, ps3 = 0, pq0 = 0, pq1 = 0, pq2 = 0, pq3 = 0;
    for (int i = rg; i < 256; i += 8) {
        const int r = r0 + i;
        if (r >= NN) break;
        ushort4 u = *(const ushort4*)&y[(size_t)r * 128 + cs];
        float f0 = bf2f(u.x), f1 = bf2f(u.y), f2v = bf2f(u.z), f3 = bf2f(u.w);
        ps0 += f0; pq0 += f0 * f0;
        ps1 += f1; pq1 += f1 * f1;
        ps2 += f2v; pq2 += f2v * f2v;
        ps3 += f3; pq3 += f3 * f3;
    }
    __shared__ float SS[8][128], SQ[8][128];
    SS[rg][cs + 0] = ps0; SS[rg][cs + 1] = ps1; SS[rg][cs + 2] = ps2; SS[rg][cs + 3] = ps3;
    SQ[rg][cs + 0] = pq0; SQ[rg][cs + 1] = pq1; SQ[rg][cs + 2] = pq2; SQ[rg][cs + 3] = pq3;
    __syncthreads();
    if (rg == 0) {
        #pragma unroll
        for (int j = 0; j < 4; ++j) {
            const int c = cs + j;
            float sv = 0, qv = 0;
            #pragma unroll
            for (int g = 0; g < 8; ++g) { sv += SS[g][c]; qv += SQ[g][c]; }
            fadd_atomic(&s[c], sv);
            fadd_atomic(&q[c], qv);
        }
    }
}

__global__ void finalize_kernel(const float* __restrict__ s, const float* __restrict__ sq,
                                const float* __restrict__ g, const float* __restrict__ bb,
                                float* __restrict__ a, float* __restrict__ c,
                                int dim, float invN)
{
    int d = blockIdx.x * blockDim.x + threadIdx.x;
    if (d >= dim) return;
    float m  = s[d] * invN;
    float v  = sq[d] * invN - m * m;
    float rs = rsqrtf(v + 1e-5f);
    float ai = g[d] * rs;
    a[d] = ai;
    c[d] = bb[d] - m * ai;
}

// h = bf16(relu(bn(y2))) in place (layer 0, 128 cols)
__global__ void bnrelu_hb_kernel(ushort* __restrict__ hb, const float* __restrict__ a,
                                 const float* __restrict__ c)
{
    int i = blockIdx.x * blockDim.x + threadIdx.x;
    const int stride = gridDim.x * blockDim.x;
    for (; i < NN * 32; i += stride) {
        const int cb = (i & 31) * 4;
        ushort4 u = *(const ushort4*)&hb[(size_t)i * 4];
        const float4 av = *(const float4*)&a[cb];
        const float4 cv = *(const float4*)&c[cb];
        ushort4 o;
        o.x = f2bf(fmaxf(fmaf(bf2f(u.x), av.x, cv.x), 0.f));
        o.y = f2bf(fmaxf(fmaf(bf2f(u.y), av.y, cv.y), 0.f));
        o.z = f2bf(fmaxf(fmaf(bf2f(u.z), av.z, cv.z), 0.f));
        o.w = f2bf(fmaxf(fmaf(bf2f(u.w), av.w, cv.w), 0.f));
        *(ushort4*)&hb[(size_t)i * 4] = o;
    }
}

// final: out[g] = bn(mean over node range of y2)  (one wave per graph)
__global__ __launch_bounds__(256) void pool_kernel(
    const ushort* __restrict__ hb, const float* __restrict__ a2, const float* __restrict__ c2,
    const int* __restrict__ gstart, float* __restrict__ out)
{
    const int g = blockIdx.x * 4 + (threadIdx.x >> 6);
    if (g >= NG) return;
    const int lane = threadIdx.x & 63;
    const int s = gstart[g], t = gstart[g + 1];
    float a0 = 0.f, a1 = 0.f;
    for (int n = s; n < t; ++n) {
        const uint v = *(const uint*)&hb[(size_t)n * 128 + lane * 2];
        a0 += __uint_as_float(v << 16);
        a1 += __uint_as_float(v & 0xffff0000u);
    }
    const int d0 = lane * 2;
    float2 o;
    if (t > s) {
        const float inv = 1.0f / (float)(t - s);
        o.x = fmaf(a2[d0 + 0], a0 * inv, c2[d0 + 0]);
        o.y = fmaf(a2[d0 + 1], a1 * inv, c2[d0 + 1]);
    } else {
        o.x = 0.f; o.y = 0.f;
    }
    *(float2*)&out[(size_t)g * 128 + d0] = o;
}

// ---------------- launch ----------------------------------------------------

extern "C" void kernel_launch(void* const* d_in, const int* in_sizes, int n_in,
                              void* d_out, int out_size, void* d_ws, size_t ws_size,
                              hipStream_t stream)
{
    (void)in_sizes; (void)n_in; (void)out_size; (void)ws_size;
    const float* x     = (const float*)d_in[0];
    const float* ea    = (const float*)d_in[1];
    const int*   src   = (const int*)d_in[2];
    const int*   dst   = (const int*)d_in[3];
    const int*   batch = (const int*)d_in[4];
    const float* W_emb = (const float*)d_in[5];
    const float* b_emb = (const float*)d_in[6];

    char* ws = (char*)d_ws;
    auto alloc = [&](size_t bytes) { void* p = ws; ws += (bytes + 255) & ~(size_t)255; return p; };

    ushort* hb   = (ushort*)alloc((size_t)NP * 128 * 2);   // 25.6 MB  h / y2 (bf16)
    float*  zf   = (float*) alloc((size_t)NP * 128 * 4);   // 51.2 MB  z (f32)
    ushort* eabc = (ushort*)alloc((size_t)EP * 128 * 2);   // 153.6 MB ea bf16, CSR order
    ushort* y1b  = (ushort*)alloc((size_t)NP * 256 * 2);   // 51.2 MB  y1 (bf16)
    int* deg    = (int*)alloc((size_t)NN * 4);
    int* offs   = (int*)alloc((size_t)(NN + 1) * 4);
    int* eperm  = (int*)alloc((size_t)NE * 4);
    int* srcp   = (int*)alloc((size_t)NE * 4);
    int* dstp   = (int*)alloc((size_t)NE * 4);
    int* csums  = (int*)alloc(128 * 4);
    int* gstart = (int*)alloc((size_t)(NG + 1) * 4);
    ushort* Wet[2], *W1t[2], *W2t[2];
    for (int l = 0; l < 2; ++l) {
        Wet[l] = (ushort*)alloc(128 * 128 * 2);
        W1t[l] = (ushort*)alloc(256 * 128 * 2);
        W2t[l] = (ushort*)alloc(128 * 256 * 2);
    }
    float* st = (float*)alloc(2048 * 4);
    float* s1 = st,        *sq1 = st + 256, *a1 = st + 512,  *c1 = st + 768;
    float* s2 = st + 1024, *sq2 = st + 1152, *a2 = st + 1280, *c2 = st + 1408;
    float* out = (float*)d_out;

    const int NCHUNK = (NN + 1023) / 1024;

    // CSR + permutation + graph boundaries (constant across layers)
    hipMemsetAsync(deg, 0, (size_t)NN * 4, stream);
    hist_kernel<<<(NE + 255) / 256, 256, 0, stream>>>(dst, deg);
    scan_chunk_kernel<<<NCHUNK, 256, 0, stream>>>(deg, offs, csums);
    scan_tops_kernel<<<1, 1, 0, stream>>>(csums, offs, NCHUNK);
    scan_add_kernel<<<(NN + 255) / 256, 256, 0, stream>>>(offs, csums);
    hipMemsetAsync(deg, 0, (size_t)NN * 4, stream);
    scatter_kernel<<<(NE + 255) / 256, 256, 0, stream>>>(dst, src, offs, deg, eperm, srcp, dstp);
    gstart_kernel<<<(NN + 256) / 256, 256, 0, stream>>>(batch, gstart);

    // one-time conversions (ea goes directly to CSR order, bias slot at col 101)
    cvt_ea_kernel<<<(NE + 7) / 8, 256, 0, stream>>>(ea, eperm, eabc);
    for (int l = 0; l < 2; ++l) {
        const float* const* L = (const float* const*)(d_in + 7 + l * 10);
        cvt_wt_kernel<<<128, 128, 0, stream>>>(L[0], Wet[l], 101, 128, 128, L[1]);  // We + be row
        cvt_wt_kernel<<<256, 128, 0, stream>>>(L[2], W1t[l], 128, 256, 128, nullptr);
        cvt_wt_kernel<<<128, 128, 0, stream>>>(L[6], W2t[l], 256, 128, 256, nullptr);
    }

    embed_kernel<<<NN / 4, 128, 0, stream>>>(x, W_emb, b_emb, hb);

    for (int layer = 0; layer < 2; ++layer) {
        const float* const* L = (const float* const*)(d_in + 7 + layer * 10);
        const float* b1  = L[3];
        const float* g1  = L[4]; const float* bb1 = L[5];
        const float* b2  = L[7];
        const float* go  = L[8]; const float* bo  = L[9];

        zinit_kernel<<<2048, 256, 0, stream>>>(hb, zf);
        edge_agg_kernel<<<1172, 256, 0, stream>>>(eabc, Wet[layer], srcp, dstp, hb, zf);

        hipMemsetAsync(s1, 0, 512 * sizeof(float), stream);
        hipMemsetAsync(s2, 0, 256 * sizeof(float), stream);

        mlp1_gemm_kernel<<<782, 256, 0, stream>>>(zf, W1t[layer], b1, y1b);
        colstats256_kernel<<<NP / 256 + 1, 256, 0, stream>>>(y1b, s1, sq1);
        finalize_kernel<<<1, 256, 0, stream>>>(s1, sq1, g1, bb1, a1, c1, 256, 1.0f / NN);
        mlp2_gemm_kernel<<<391, 256, 0, stream>>>(y1b, a1, c1, W2t[layer], b2, hb);
        colstats128b_kernel<<<NP / 256 + 1, 256, 0, stream>>>(hb, s2, sq2);
        finalize_kernel<<<1, 128, 0, stream>>>(s2, sq2, go, bo, a2, c2, 128, 1.0f / NN);

        if (layer == 0) {
            bnrelu_hb_kernel<<<2048, 256, 0, stream>>>(hb, a2, c2);
        } else {
            pool_kernel<<<NG / 4, 256, 0, stream>>>(hb, a2, c2, gstart, out);
        }
    }
}

// Round 10
// 1136.663 us; speedup vs baseline: 1.0301x; 1.0301x over previous
//
#include <hip/hip_runtime.h>
#include <cstddef>

#define NN  100000
#define NE  600000
#define NG  4096
#define DIN 73
#define DE  101
#define DD  128
#define DD2 256
#define NP  100096   // NN padded to 64-row tiles
#define EP  600064   // NE padded to 128-row tiles (4688 tiles)
#define NT  (EP / 128)

typedef unsigned int uint;
typedef unsigned short ushort;
typedef __attribute__((ext_vector_type(8))) short bf16x8;
typedef __attribute__((ext_vector_type(4))) float f32x4;

__device__ __forceinline__ void fadd_atomic(float* p, float v) { unsafeAtomicAdd(p, v); }

__device__ __forceinline__ ushort f2bf(float f) {   // RNE f32->bf16
    uint u = __float_as_uint(f);
    uint r = (u + 0x7fffu + ((u >> 16) & 1u)) >> 16;
    return (ushort)r;
}
__device__ __forceinline__ float bf2f(ushort u) { return __uint_as_float(((uint)u) << 16); }

// f32x8 -> bf16x8 fragment (for mlp1 reading f32 z)
__device__ __forceinline__ bf16x8 ld_zfrag(const float* __restrict__ p) {
    const float4 f0 = *(const float4*)p;
    const float4 f1 = *(const float4*)(p + 4);
    bf16x8 r;
    r[0] = (short)f2bf(f0.x); r[1] = (short)f2bf(f0.y);
    r[2] = (short)f2bf(f0.z); r[3] = (short)f2bf(f0.w);
    r[4] = (short)f2bf(f1.x); r[5] = (short)f2bf(f1.y);
    r[6] = (short)f2bf(f1.z); r[7] = (short)f2bf(f1.w);
    return r;
}

// ---------------- CSR build (once per call) ---------------------------------

__global__ void hist_kernel(const int* __restrict__ dst, int* __restrict__ deg) {
    int e = blockIdx.x * blockDim.x + threadIdx.x;
    if (e < NE) atomicAdd(&deg[dst[e]], 1);
}

__global__ __launch_bounds__(256) void scan_chunk_kernel(
    const int* __restrict__ deg, int* __restrict__ offs, int* __restrict__ csums)
{
    const int b = blockIdx.x, t = threadIdx.x;
    const int base = b * 1024 + t * 4;
    int v[4];
    #pragma unroll
    for (int i = 0; i < 4; ++i) v[i] = (base + i < NN) ? deg[base + i] : 0;
    int tsum = v[0] + v[1] + v[2] + v[3];
    const int lane = t & 63, w = t >> 6;
    int x = tsum;
    #pragma unroll
    for (int d = 1; d < 64; d <<= 1) {
        int y = __shfl_up(x, d, 64);
        if (lane >= d) x += y;
    }
    __shared__ int wsum[4];
    if (lane == 63) wsum[w] = x;
    __syncthreads();
    int woff = 0;
    for (int i = 0; i < w; ++i) woff += wsum[i];
    int run = woff + x - tsum;
    #pragma unroll
    for (int i = 0; i < 4; ++i) {
        if (base + i < NN) offs[base + i] = run;
        run += v[i];
    }
    if (t == 255) csums[b] = woff + x;
}

__global__ void scan_tops_kernel(int* __restrict__ csums, int* __restrict__ offs, int nchunks) {
    if (threadIdx.x == 0 && blockIdx.x == 0) {
        int run = 0;
        for (int i = 0; i < nchunks; ++i) { int c = csums[i]; csums[i] = run; run += c; }
        offs[NN] = run;
    }
}

__global__ void scan_add_kernel(int* __restrict__ offs, const int* __restrict__ csums) {
    int i = blockIdx.x * blockDim.x + threadIdx.x;
    if (i < NN) offs[i] += csums[i >> 10];
}

// builds eperm (edge -> csr position), srcp and dstp (csr-ordered src/dst)
__global__ void scatter_kernel(const int* __restrict__ dst, const int* __restrict__ src,
                               const int* __restrict__ offs, int* __restrict__ cursor,
                               int* __restrict__ eperm, int* __restrict__ srcp,
                               int* __restrict__ dstp)
{
    int e = blockIdx.x * blockDim.x + threadIdx.x;
    if (e >= NE) return;
    int d = dst[e];
    int pos = offs[d] + atomicAdd(&cursor[d], 1);
    eperm[e] = pos;
    srcp[pos] = src[e];
    dstp[pos] = d;
}

__global__ void gstart_kernel(const int* __restrict__ batch, int* __restrict__ gstart) {
    int n = blockIdx.x * blockDim.x + threadIdx.x;
    if (n > NN) return;
    if (n == NN) {
        for (int g = batch[NN - 1] + 1; g <= NG; ++g) gstart[g] = NN;
        return;
    }
    int b = batch[n];
    int pb = (n == 0) ? -1 : batch[n - 1];
    for (int g = pb + 1; g <= b; ++g) gstart[g] = n;
}

// per-tile segment metadata (graph-static, built once):
// segpack[t*128+s] = node(17b) | rowstart(7b)<<17 | (len-1)(7b)<<24 | boundary(1b)<<31
__global__ __launch_bounds__(128) void segbuild_kernel(const int* __restrict__ dstp,
                                                       uint* __restrict__ segpack,
                                                       int* __restrict__ nsegs)
{
    const int t = blockIdx.x, r = threadIdx.x;
    const int rr = t * 128 + r;
    __shared__ int nd[128];
    __shared__ int sc[128];
    nd[r] = (rr < NE) ? dstp[rr] : NN;
    __syncthreads();
    const int flag = (r == 0 || nd[r] != nd[r - 1]) ? 1 : 0;
    sc[r] = flag;
    __syncthreads();
    for (int d = 1; d < 128; d <<= 1) {
        int v = (r >= d) ? sc[r - d] : 0;
        __syncthreads();
        sc[r] += v;
        __syncthreads();
    }
    const int total = sc[127];
    if (flag) {
        const int s = sc[r] - 1;
        int len = 1;
        while (r + len < 128 && nd[r + len] == nd[r]) ++len;
        const uint bnd = (s == 0 || s == total - 1) ? 1u : 0u;
        segpack[(size_t)t * 128 + s] =
            ((uint)nd[r]) | ((uint)r << 17) | ((uint)(len - 1) << 24) | (bnd << 31);
    }
    if (r == 0) nsegs[t] = total;
}

// ---------------- conversions ----------------------------------------------

// ea f32 [E,101] -> bf16 [EP,128] in CSR order; col 101 = 1.0 (bias slot)
__global__ __launch_bounds__(256) void cvt_ea_kernel(const float* __restrict__ ea,
                                                     const int* __restrict__ eperm,
                                                     ushort* __restrict__ eabc)
{
    const int t = threadIdx.x;
    const int r = blockIdx.x * 8 + (t >> 5);
    if (r >= NE) return;
    const int pos = eperm[r];
    const int c = (t & 31) * 4;
    ushort4 o;
    #pragma unroll
    for (int i = 0; i < 4; ++i) {
        const int col = c + i;
        float v = (col < DE) ? ea[(size_t)r * DE + col] : ((col == DE) ? 1.0f : 0.0f);
        ((ushort*)&o)[i] = f2bf(v);
    }
    *(ushort4*)&eabc[(size_t)pos * 128 + c] = o;
}

// in f32 [Kin,Nn] -> out bf16 [Nn][Kp] transposed; row Kin = bias (if given), rest 0
__global__ void cvt_wt_kernel(const float* __restrict__ in, ushort* __restrict__ out,
                              int Kin, int Nn, int Kp, const float* __restrict__ bias)
{
    const int n = blockIdx.x;
    for (int k = threadIdx.x; k < Kp; k += blockDim.x) {
        float v = 0.0f;
        if (k < Kin) v = in[(size_t)k * Nn + n];
        else if (k == Kin && bias) v = bias[n];
        out[(size_t)n * Kp + k] = f2bf(v);
    }
}

// ---------------- fused edge GEMM + segment-sum aggregation ------------------
// e = eabc@We(+be via K-slot); val = relu(e + h[srcp]); zf[dst] += segment sums.
// Reduce phase is PARALLEL over (segment x column) pairs using precomputed
// per-tile segment metadata; interior segments (exclusively owned) use plain
// stores, only tile-boundary segments use atomics (~1.2M vs 12.7M per layer).
__global__ __launch_bounds__(256, 2) void edge_agg_kernel(
    const ushort* __restrict__ eab, const ushort* __restrict__ Wt,
    const int* __restrict__ srcp, const uint* __restrict__ segpack,
    const int* __restrict__ nsegs, const ushort* __restrict__ hb,
    float* __restrict__ zf)
{
    __shared__ ushort vals[128 * 128];   // [row][col], col XOR-swizzled by row
    const int tid = threadIdx.x;
    const int wid = tid >> 6;
    const int msub = wid >> 1, nsl = wid & 1;
    const int lane = tid & 63, l15 = lane & 15, grp = lane >> 4;
    const int n0 = nsl * 64;

    bf16x8 A[4][4];
    #pragma unroll
    for (int nf = 0; nf < 4; ++nf)
        #pragma unroll
        for (int kk = 0; kk < 4; ++kk)
            A[nf][kk] = *(const bf16x8*)(Wt + (size_t)(n0 + nf * 16 + l15) * 128 + kk * 32 + grp * 8);

    for (int t = blockIdx.x; t < NT; t += gridDim.x) {
        const int m0 = t * 128 + msub * 64;
        __syncthreads();          // previous tile's reduce done before overwriting LDS
        // issue h-gather early (hides under MFMA)
        int sp[4];
        #pragma unroll
        for (int mf = 0; mf < 4; ++mf) {
            const int rr = m0 + mf * 16 + l15;
            sp[mf] = (rr < NE) ? srcp[rr] : 0;
        }
        ushort4 hv[4][4];
        #pragma unroll
        for (int mf = 0; mf < 4; ++mf)
            #pragma unroll
            for (int nf = 0; nf < 4; ++nf)
                hv[mf][nf] = *(const ushort4*)&hb[(size_t)sp[mf] * 128 + n0 + nf * 16 + grp * 4];
        // GEMM
        f32x4 acc[4][4];
        #pragma unroll
        for (int i = 0; i < 4; ++i)
            #pragma unroll
            for (int j = 0; j < 4; ++j) acc[i][j] = (f32x4){0.f, 0.f, 0.f, 0.f};
        #pragma unroll
        for (int kk = 0; kk < 4; ++kk) {
            bf16x8 b[4];
            #pragma unroll
            for (int mf = 0; mf < 4; ++mf)
                b[mf] = *(const bf16x8*)(eab + (size_t)(m0 + mf * 16 + l15) * 128 + kk * 32 + grp * 8);
            #pragma unroll
            for (int mf = 0; mf < 4; ++mf)
                #pragma unroll
                for (int nf = 0; nf < 4; ++nf)
                    acc[mf][nf] = __builtin_amdgcn_mfma_f32_16x16x32_bf16(A[nf][kk], b[mf], acc[mf][nf], 0, 0, 0);
        }
        // relu(e + h) -> LDS (swizzled: ushort-index col ^ ((row&7)<<3))
        #pragma unroll
        for (int mf = 0; mf < 4; ++mf) {
            const int row = msub * 64 + mf * 16 + l15;
            const int sw = (row & 7) << 3;
            #pragma unroll
            for (int nf = 0; nf < 4; ++nf) {
                const int col = n0 + nf * 16 + grp * 4;
                ushort4 o;
                o.x = f2bf(fmaxf(acc[mf][nf][0] + bf2f(hv[mf][nf].x), 0.f));
                o.y = f2bf(fmaxf(acc[mf][nf][1] + bf2f(hv[mf][nf].y), 0.f));
                o.z = f2bf(fmaxf(acc[mf][nf][2] + bf2f(hv[mf][nf].z), 0.f));
                o.w = f2bf(fmaxf(acc[mf][nf][3] + bf2f(hv[mf][nf].w), 0.f));
                *(ushort4*)&vals[row * 128 + (col ^ sw)] = o;
            }
        }
        __syncthreads();
        // parallel segment reduce over (segment, column) pairs
        const int ns = nsegs[t];
        const uint* spk = &segpack[(size_t)t * 128];
        for (int p = tid; p < ns * 128; p += 256) {
            const int s = p >> 7, col = p & 127;
            const uint m = spk[s];
            const int node = m & 0x1FFFF;
            if (node >= NN) continue;
            const int start = (m >> 17) & 127;
            const int len = (int)((m >> 24) & 127) + 1;
            float sum = 0.f;
            for (int r = start; r < start + len; ++r)
                sum += bf2f(vals[r * 128 + (col ^ ((r & 7) << 3))]);
            float* zp = &zf[(size_t)node * 128 + col];
            if (m >> 31) fadd_atomic(zp, sum);
            else *zp = bf2f(hb[(size_t)node * 128 + col]) + sum;
        }
    }
}

// zf = f32(hb) for rows < NN, 0 for padded rows
__global__ void zinit_kernel(const ushort* __restrict__ hb, float* __restrict__ zf) {
    int i = blockIdx.x * blockDim.x + threadIdx.x;
    const int stride = gridDim.x * blockDim.x;
    for (; i < NP * 32; i += stride) {
        const int n = i >> 5;
        float4 o;
        if (n < NN) {
            ushort4 u = *(const ushort4*)&hb[(size_t)i * 4];
            o.x = bf2f(u.x); o.y = bf2f(u.y); o.z = bf2f(u.z); o.w = bf2f(u.w);
        } else {
            o.x = 0.f; o.y = 0.f; o.z = 0.f; o.w = 0.f;
        }
        *(float4*)&zf[(size_t)i * 4] = o;
    }
}

// ---------------- weight-stationary MFMA GEMMs ------------------------------

// mlp1: y1 = z@W1 + b1 -> bf16 [NP,256]; z is f32, converted in-register
__global__ __launch_bounds__(256, 2) void mlp1_gemm_kernel(
    const float* __restrict__ z, const ushort* __restrict__ Wt,
    const float* __restrict__ bias, ushort* __restrict__ y)
{
    const int n0 = (threadIdx.x >> 6) * 64;
    const int lane = threadIdx.x & 63, l15 = lane & 15, grp = lane >> 4;
    bf16x8 A[4][4];
    #pragma unroll
    for (int nf = 0; nf < 4; ++nf)
        #pragma unroll
        for (int kk = 0; kk < 4; ++kk)
            A[nf][kk] = *(const bf16x8*)(Wt + (size_t)(n0 + nf * 16 + l15) * 128 + kk * 32 + grp * 8);
    float4 bv[4];
    #pragma unroll
    for (int nf = 0; nf < 4; ++nf) bv[nf] = *(const float4*)&bias[n0 + nf * 16 + grp * 4];

    const int ntiles = NP / 64;   // 1564
    for (int t = blockIdx.x; t < ntiles; t += gridDim.x) {
        const int m0 = t * 64;
        f32x4 acc[4][4];
        #pragma unroll
        for (int i = 0; i < 4; ++i)
            #pragma unroll
            for (int j = 0; j < 4; ++j) acc[i][j] = (f32x4){0.f, 0.f, 0.f, 0.f};
        #pragma unroll
        for (int kk = 0; kk < 4; ++kk) {
            bf16x8 b[4];
            #pragma unroll
            for (int mf = 0; mf < 4; ++mf)
                b[mf] = ld_zfrag(z + (size_t)(m0 + mf * 16 + l15) * 128 + kk * 32 + grp * 8);
            #pragma unroll
            for (int mf = 0; mf < 4; ++mf)
                #pragma unroll
                for (int nf = 0; nf < 4; ++nf)
                    acc[mf][nf] = __builtin_amdgcn_mfma_f32_16x16x32_bf16(A[nf][kk], b[mf], acc[mf][nf], 0, 0, 0);
        }
        #pragma unroll
        for (int mf = 0; mf < 4; ++mf) {
            ushort* rp = &y[(size_t)(m0 + mf * 16 + l15) * 256 + n0];
            #pragma unroll
            for (int nf = 0; nf < 4; ++nf) {
                ushort4 o;
                o.x = f2bf(acc[mf][nf][0] + bv[nf].x);
                o.y = f2bf(acc[mf][nf][1] + bv[nf].y);
                o.z = f2bf(acc[mf][nf][2] + bv[nf].z);
                o.w = f2bf(acc[mf][nf][3] + bv[nf].w);
                *(ushort4*)&rp[nf * 16 + grp * 4] = o;
            }
        }
    }
}

// mlp2: y2 = y1r@W2 + b2 -> bf16 [NP,128]  (y1r pre-activated in place), K=256
__global__ __launch_bounds__(256, 2) void mlp2_gemm_kernel(
    const ushort* __restrict__ y1, const ushort* __restrict__ Wt,
    const float* __restrict__ bias, ushort* __restrict__ y2)
{
    const int wid = threadIdx.x >> 6;
    const int msub = wid >> 1, nsl = wid & 1;
    const int lane = threadIdx.x & 63, l15 = lane & 15, grp = lane >> 4;
    const int n0 = nsl * 64;
    bf16x8 A[4][8];
    #pragma unroll
    for (int nf = 0; nf < 4; ++nf)
        #pragma unroll
        for (int kk = 0; kk < 8; ++kk)
            A[nf][kk] = *(const bf16x8*)(Wt + (size_t)(n0 + nf * 16 + l15) * 256 + kk * 32 + grp * 8);
    float4 bv[4];
    #pragma unroll
    for (int nf = 0; nf < 4; ++nf) bv[nf] = *(const float4*)&bias[n0 + nf * 16 + grp * 4];

    const int ntiles = NP / 128;   // 782
    for (int t = blockIdx.x; t < ntiles; t += gridDim.x) {
        const int m0 = t * 128 + msub * 64;
        f32x4 acc[4][4];
        #pragma unroll
        for (int i = 0; i < 4; ++i)
            #pragma unroll
            for (int j = 0; j < 4; ++j) acc[i][j] = (f32x4){0.f, 0.f, 0.f, 0.f};
        #pragma unroll
        for (int kk = 0; kk < 8; ++kk) {
            bf16x8 b[4];
            #pragma unroll
            for (int mf = 0; mf < 4; ++mf)
                b[mf] = *(const bf16x8*)(y1 + (size_t)(m0 + mf * 16 + l15) * 256 + kk * 32 + grp * 8);
            #pragma unroll
            for (int mf = 0; mf < 4; ++mf)
                #pragma unroll
                for (int nf = 0; nf < 4; ++nf)
                    acc[mf][nf] = __builtin_amdgcn_mfma_f32_16x16x32_bf16(A[nf][kk], b[mf], acc[mf][nf], 0, 0, 0);
        }
        #pragma unroll
        for (int mf = 0; mf < 4; ++mf) {
            ushort* rp = &y2[(size_t)(m0 + mf * 16 + l15) * 128 + n0];
            #pragma unroll
            for (int nf = 0; nf < 4; ++nf) {
                ushort4 o;
                o.x = f2bf(acc[mf][nf][0] + bv[nf].x);
                o.y = f2bf(acc[mf][nf][1] + bv[nf].y);
                o.z = f2bf(acc[mf][nf][2] + bv[nf].z);
                o.w = f2bf(acc[mf][nf][3] + bv[nf].w);
                *(ushort4*)&rp[nf * 16 + grp * 4] = o;
            }
        }
    }
}

// ---------------- elementwise / stats kernels --------------------------------

// h = bf16(x @ W_emb + b_emb)  (runs once)
__global__ __launch_bounds__(128) void embed_kernel(
    const float* __restrict__ x, const float* __restrict__ W,
    const float* __restrict__ b, ushort* __restrict__ hb)
{
    __shared__ float xs[4][DIN];
    const int n0 = blockIdx.x * 4;
    const int d  = threadIdx.x;
    for (int idx = d; idx < 4 * DIN; idx += 128) {
        int r = idx / DIN, c = idx - r * DIN;
        xs[r][c] = x[(size_t)n0 * DIN + idx];
    }
    __syncthreads();
    float bb = b[d];
    float a0 = bb, a1 = bb, a2 = bb, a3 = bb;
    for (int k = 0; k < DIN; ++k) {
        float w = W[k * DD + d];
        a0 = fmaf(xs[0][k], w, a0);
        a1 = fmaf(xs[1][k], w, a1);
        a2 = fmaf(xs[2][k], w, a2);
        a3 = fmaf(xs[3][k], w, a3);
    }
    hb[(size_t)(n0 + 0) * DD + d] = f2bf(a0);
    hb[(size_t)(n0 + 1) * DD + d] = f2bf(a1);
    hb[(size_t)(n0 + 2) * DD + d] = f2bf(a2);
    hb[(size_t)(n0 + 3) * DD + d] = f2bf(a3);
}

// column sums/sumsq of bf16 [*,256], rows < NN
__global__ __launch_bounds__(256) void colstats256_kernel(
    const ushort* __restrict__ y, float* __restrict__ s, float* __restrict__ q)
{
    const int t = threadIdx.x;
    const int cs = (t & 63) * 4, rg = t >> 6;
    const int r0 = blockIdx.x * 256;
    float ps0 = 0, ps1 = 0, ps2 = 0, ps3 = 0, pq0 = 0, pq1 = 0, pq2 = 0, pq3 = 0;
    for (int i = rg; i < 256; i += 4) {
        const int r = r0 + i;
        if (r >= NN) break;
        ushort4 u = *(const ushort4*)&y[(size_t)r * 256 + cs];
        float f0 = bf2f(u.x), f1 = bf2f(u.y), f2v = bf2f(u.z), f3 = bf2f(u.w);
        ps0 += f0; pq0 += f0 * f0;
        ps1 += f1; pq1 += f1 * f1;
        ps2 += f2v; pq2 += f2v * f2v;
        ps3 += f3; pq3 += f3 * f3;
    }
    __shared__ float SS[4][256], SQ[4][256];
    SS[rg][cs + 0] = ps0; SS[rg][cs + 1] = ps1; SS[rg][cs + 2] = ps2; SS[rg][cs + 3] = ps3;
    SQ[rg][cs + 0] = pq0; SQ[rg][cs + 1] = pq1; SQ[rg][cs + 2] = pq2; SQ[rg][cs + 3] = pq3;
    __syncthreads();
    if (rg == 0) {
        #pragma unroll
        for (int j = 0; j < 4; ++j) {
            const int c = cs + j;
            fadd_atomic(&s[c], SS[0][c] + SS[1][c] + SS[2][c] + SS[3][c]);
            fadd_atomic(&q[c], SQ[0][c] + SQ[1][c] + SQ[2][c] + SQ[3][c]);
        }
    }
}

// column sums/sumsq of bf16 [*,128], rows < NN
__global__ __launch_bounds__(256) void colstats128b_kernel(
    const ushort* __restrict__ y, float* __restrict__ s, float* __restrict__ q)
{
    const int t = threadIdx.x;
    const int cs = (t & 31) * 4, rg = t >> 5;
    const int r0 = blockIdx.x * 256;
    float ps0 = 0, ps1 = 0, ps2 = 0, ps3 = 0, pq0 = 0, pq1 = 0, pq2 = 0, pq3 = 0;
    for (int i = rg; i < 256; i += 8) {
        const int r = r0 + i;
        if (r >= NN) break;
        ushort4 u = *(const ushort4*)&y[(size_t)r * 128 + cs];
        float f0 = bf2f(u.x), f1 = bf2f(u.y), f2v = bf2f(u.z), f3 = bf2f(u.w);
        ps0 += f0; pq0 += f0 * f0;
        ps1 += f1; pq1 += f1 * f1;
        ps2 += f2v; pq2 += f2v * f2v;
        ps3 += f3; pq3 += f3 * f3;
    }
    __shared__ float SS[8][128], SQ[8][128];
    SS[rg][cs + 0] = ps0; SS[rg][cs + 1] = ps1; SS[rg][cs + 2] = ps2; SS[rg][cs + 3] = ps3;
    SQ[rg][cs + 0] = pq0; SQ[rg][cs + 1] = pq1; SQ[rg][cs + 2] = pq2; SQ[rg][cs + 3] = pq3;
    __syncthreads();
    if (rg == 0) {
        #pragma unroll
        for (int j = 0; j < 4; ++j) {
            const int c = cs + j;
            float sv = 0, qv = 0;
            #pragma unroll
            for (int g = 0; g < 8; ++g) { sv += SS[g][c]; qv += SQ[g][c]; }
            fadd_atomic(&s[c], sv);
            fadd_atomic(&q[c], qv);
        }
    }
}

__global__ void finalize_kernel(const float* __restrict__ s, const float* __restrict__ sq,
                                const float* __restrict__ g, const float* __restrict__ bb,
                                float* __restrict__ a, float* __restrict__ c,
                                int dim, float invN)
{
    int d = blockIdx.x * blockDim.x + threadIdx.x;
    if (d >= dim) return;
    float m  = s[d] * invN;
    float v  = sq[d] * invN - m * m;
    float rs = rsqrtf(v + 1e-5f);
    float ai = g[d] * rs;
    a[d] = ai;
    c[d] = bb[d] - m * ai;
}

// y1 = bf16(relu(bn1(y1))) in place, rows < NN  (256 cols)
__global__ void bnrelu_bf_kernel(ushort* __restrict__ y, const float* __restrict__ a,
                                 const float* __restrict__ c)
{
    int i = blockIdx.x * blockDim.x + threadIdx.x;
    const int stride = gridDim.x * blockDim.x;
    for (; i < NN * 64; i += stride) {
        const int cb = (i & 63) * 4;
        ushort4 u = *(const ushort4*)&y[(size_t)i * 4];
        const float4 av = *(const float4*)&a[cb];
        const float4 cv = *(const float4*)&c[cb];
        ushort4 o;
        o.x = f2bf(fmaxf(fmaf(bf2f(u.x), av.x, cv.x), 0.f));
        o.y = f2bf(fmaxf(fmaf(bf2f(u.y), av.y, cv.y), 0.f));
        o.z = f2bf(fmaxf(fmaf(bf2f(u.z), av.z, cv.z), 0.f));
        o.w = f2bf(fmaxf(fmaf(bf2f(u.w), av.w, cv.w), 0.f));
        *(ushort4*)&y[(size_t)i * 4] = o;
    }
}

// h = bf16(relu(bn(y2))) in place (layer 0, 128 cols)
__global__ void bnrelu_hb_kernel(ushort* __restrict__ hb, const float* __restrict__ a,
                                 const float* __restrict__ c)
{
    int i = blockIdx.x * blockDim.x + threadIdx.x;
    const int stride = gridDim.x * blockDim.x;
    for (; i < NN * 32; i += stride) {
        const int cb = (i & 31) * 4;
        ushort4 u = *(const ushort4*)&hb[(size_t)i * 4];
        const float4 av = *(const float4*)&a[cb];
        const float4 cv = *(const float4*)&c[cb];
        ushort4 o;
        o.x = f2bf(fmaxf(fmaf(bf2f(u.x), av.x, cv.x), 0.f));
        o.y = f2bf(fmaxf(fmaf(bf2f(u.y), av.y, cv.y), 0.f));
        o.z = f2bf(fmaxf(fmaf(bf2f(u.z), av.z, cv.z), 0.f));
        o.w = f2bf(fmaxf(fmaf(bf2f(u.w), av.w, cv.w), 0.f));
        *(ushort4*)&hb[(size_t)i * 4] = o;
    }
}

// final: out[g] = bn(mean over node range of y2)  (one wave per graph)
__global__ __launch_bounds__(256) void pool_kernel(
    const ushort* __restrict__ hb, const float* __restrict__ a2, const float* __restrict__ c2,
    const int* __restrict__ gstart, float* __restrict__ out)
{
    const int g = blockIdx.x * 4 + (threadIdx.x >> 6);
    if (g >= NG) return;
    const int lane = threadIdx.x & 63;
    const int s = gstart[g], t = gstart[g + 1];
    float a0 = 0.f, a1 = 0.f;
    for (int n = s; n < t; ++n) {
        const uint v = *(const uint*)&hb[(size_t)n * 128 + lane * 2];
        a0 += __uint_as_float(v << 16);
        a1 += __uint_as_float(v & 0xffff0000u);
    }
    const int d0 = lane * 2;
    float2 o;
    if (t > s) {
        const float inv = 1.0f / (float)(t - s);
        o.x = fmaf(a2[d0 + 0], a0 * inv, c2[d0 + 0]);
        o.y = fmaf(a2[d0 + 1], a1 * inv, c2[d0 + 1]);
    } else {
        o.x = 0.f; o.y = 0.f;
    }
    *(float2*)&out[(size_t)g * 128 + d0] = o;
}

// ---------------- launch ----------------------------------------------------

extern "C" void kernel_launch(void* const* d_in, const int* in_sizes, int n_in,
                              void* d_out, int out_size, void* d_ws, size_t ws_size,
                              hipStream_t stream)
{
    (void)in_sizes; (void)n_in; (void)out_size; (void)ws_size;
    const float* x     = (const float*)d_in[0];
    const float* ea    = (const float*)d_in[1];
    const int*   src   = (const int*)d_in[2];
    const int*   dst   = (const int*)d_in[3];
    const int*   batch = (const int*)d_in[4];
    const float* W_emb = (const float*)d_in[5];
    const float* b_emb = (const float*)d_in[6];

    char* ws = (char*)d_ws;
    auto alloc = [&](size_t bytes) { void* p = ws; ws += (bytes + 255) & ~(size_t)255; return p; };

    ushort* hb   = (ushort*)alloc((size_t)NP * 128 * 2);   // 25.6 MB  h / y2 (bf16)
    float*  zf   = (float*) alloc((size_t)NP * 128 * 4);   // 51.2 MB  z (f32)
    ushort* eabc = (ushort*)alloc((size_t)EP * 128 * 2);   // 153.6 MB ea bf16, CSR order
    ushort* y1b  = (ushort*)alloc((size_t)NP * 256 * 2);   // 51.2 MB  y1 (bf16)
    int* deg    = (int*)alloc((size_t)NN * 4);
    int* offs   = (int*)alloc((size_t)(NN + 1) * 4);
    int* eperm  = (int*)alloc((size_t)NE * 4);
    int* srcp   = (int*)alloc((size_t)NE * 4);
    int* dstp   = (int*)alloc((size_t)NE * 4);
    int* csums  = (int*)alloc(128 * 4);
    int* gstart = (int*)alloc((size_t)(NG + 1) * 4);
    uint* segpack = (uint*)alloc((size_t)NT * 128 * 4);    // 2.4 MB
    int*  nsegs   = (int*)alloc((size_t)NT * 4);
    ushort* Wet[2], *W1t[2], *W2t[2];
    for (int l = 0; l < 2; ++l) {
        Wet[l] = (ushort*)alloc(128 * 128 * 2);
        W1t[l] = (ushort*)alloc(256 * 128 * 2);
        W2t[l] = (ushort*)alloc(128 * 256 * 2);
    }
    float* st = (float*)alloc(2048 * 4);
    float* s1 = st,        *sq1 = st + 256, *a1 = st + 512,  *c1 = st + 768;
    float* s2 = st + 1024, *sq2 = st + 1152, *a2 = st + 1280, *c2 = st + 1408;
    float* out = (float*)d_out;

    const int NCHUNK = (NN + 1023) / 1024;

    // CSR + permutation + graph boundaries (constant across layers)
    hipMemsetAsync(deg, 0, (size_t)NN * 4, stream);
    hist_kernel<<<(NE + 255) / 256, 256, 0, stream>>>(dst, deg);
    scan_chunk_kernel<<<NCHUNK, 256, 0, stream>>>(deg, offs, csums);
    scan_tops_kernel<<<1, 1, 0, stream>>>(csums, offs, NCHUNK);
    scan_add_kernel<<<(NN + 255) / 256, 256, 0, stream>>>(offs, csums);
    hipMemsetAsync(deg, 0, (size_t)NN * 4, stream);
    scatter_kernel<<<(NE + 255) / 256, 256, 0, stream>>>(dst, src, offs, deg, eperm, srcp, dstp);
    gstart_kernel<<<(NN + 256) / 256, 256, 0, stream>>>(batch, gstart);
    segbuild_kernel<<<NT, 128, 0, stream>>>(dstp, segpack, nsegs);

    // one-time conversions (ea goes directly to CSR order, bias slot at col 101)
    cvt_ea_kernel<<<(NE + 7) / 8, 256, 0, stream>>>(ea, eperm, eabc);
    for (int l = 0; l < 2; ++l) {
        const float* const* L = (const float* const*)(d_in + 7 + l * 10);
        cvt_wt_kernel<<<128, 128, 0, stream>>>(L[0], Wet[l], 101, 128, 128, L[1]);  // We + be row
        cvt_wt_kernel<<<256, 128, 0, stream>>>(L[2], W1t[l], 128, 256, 128, nullptr);
        cvt_wt_kernel<<<128, 128, 0, stream>>>(L[6], W2t[l], 256, 128, 256, nullptr);
    }

    embed_kernel<<<NN / 4, 128, 0, stream>>>(x, W_emb, b_emb, hb);

    for (int layer = 0; layer < 2; ++layer) {
        const float* const* L = (const float* const*)(d_in + 7 + layer * 10);
        const float* b1  = L[3];
        const float* g1  = L[4]; const float* bb1 = L[5];
        const float* b2  = L[7];
        const float* go  = L[8]; const float* bo  = L[9];

        zinit_kernel<<<2048, 256, 0, stream>>>(hb, zf);
        edge_agg_kernel<<<1172, 256, 0, stream>>>(eabc, Wet[layer], srcp, segpack, nsegs, hb, zf);

        hipMemsetAsync(s1, 0, 512 * sizeof(float), stream);
        hipMemsetAsync(s2, 0, 256 * sizeof(float), stream);

        mlp1_gemm_kernel<<<782, 256, 0, stream>>>(zf, W1t[layer], b1, y1b);
        colstats256_kernel<<<NP / 256 + 1, 256, 0, stream>>>(y1b, s1, sq1);
        finalize_kernel<<<1, 256, 0, stream>>>(s1, sq1, g1, bb1, a1, c1, 256, 1.0f / NN);
        bnrelu_bf_kernel<<<2048, 256, 0, stream>>>(y1b, a1, c1);
        mlp2_gemm_kernel<<<391, 256, 0, stream>>>(y1b, W2t[layer], b2, hb);
        colstats128b_kernel<<<NP / 256 + 1, 256, 0, stream>>>(hb, s2, sq2);
        finalize_kernel<<<1, 128, 0, stream>>>(s2, sq2, go, bo, a2, c2, 128, 1.0f / NN);

        if (layer == 0) {
            bnrelu_hb_kernel<<<2048, 256, 0, stream>>>(hb, a2, c2);
        } else {
            pool_kernel<<<NG / 4, 256, 0, stream>>>(hb, a2, c2, gstart, out);
        }
    }
}

// Round 11
// 1029.799 us; speedup vs baseline: 1.1369x; 1.1038x over previous
//
#include <hip/hip_runtime.h>
#include <cstddef>

#define NN  100000
#define NE  600000
#define NG  4096
#define DIN 73
#define DE  101
#define DD  128
#define DD2 256
#define NP  100096   // NN padded to 64-row tiles
#define EP  600064   // NE padded to 128-row tiles (4688 tiles)

typedef unsigned int uint;
typedef unsigned short ushort;
typedef __attribute__((ext_vector_type(8))) short bf16x8;
typedef __attribute__((ext_vector_type(4))) float f32x4;

__device__ __forceinline__ void fadd_atomic(float* p, float v) { unsafeAtomicAdd(p, v); }

__device__ __forceinline__ ushort f2bf(float f) {   // RNE f32->bf16
    uint u = __float_as_uint(f);
    uint r = (u + 0x7fffu + ((u >> 16) & 1u)) >> 16;
    return (ushort)r;
}
__device__ __forceinline__ float bf2f(ushort u) { return __uint_as_float(((uint)u) << 16); }

// f32x8 -> bf16x8 fragment (for mlp1 reading f32 z)
__device__ __forceinline__ bf16x8 ld_zfrag(const float* __restrict__ p) {
    const float4 f0 = *(const float4*)p;
    const float4 f1 = *(const float4*)(p + 4);
    bf16x8 r;
    r[0] = (short)f2bf(f0.x); r[1] = (short)f2bf(f0.y);
    r[2] = (short)f2bf(f0.z); r[3] = (short)f2bf(f0.w);
    r[4] = (short)f2bf(f1.x); r[5] = (short)f2bf(f1.y);
    r[6] = (short)f2bf(f1.z); r[7] = (short)f2bf(f1.w);
    return r;
}

// LDS-only barrier: orders all LDS ops (lgkmcnt) across the workgroup but does
// NOT drain vmcnt -- fire-and-forget zf atomics stay in flight across tiles.
// Safe here: post-barrier code never depends on the atomics' completion, and
// the atomics read register operands, not LDS.
#define BARRIER_LDS() asm volatile("s_waitcnt lgkmcnt(0)\n\ts_barrier" ::: "memory")

// ---------------- CSR build (once per call) ---------------------------------

__global__ void hist_kernel(const int* __restrict__ dst, int* __restrict__ deg) {
    int e = blockIdx.x * blockDim.x + threadIdx.x;
    if (e < NE) atomicAdd(&deg[dst[e]], 1);
}

__global__ __launch_bounds__(256) void scan_chunk_kernel(
    const int* __restrict__ deg, int* __restrict__ offs, int* __restrict__ csums)
{
    const int b = blockIdx.x, t = threadIdx.x;
    const int base = b * 1024 + t * 4;
    int v[4];
    #pragma unroll
    for (int i = 0; i < 4; ++i) v[i] = (base + i < NN) ? deg[base + i] : 0;
    int tsum = v[0] + v[1] + v[2] + v[3];
    const int lane = t & 63, w = t >> 6;
    int x = tsum;
    #pragma unroll
    for (int d = 1; d < 64; d <<= 1) {
        int y = __shfl_up(x, d, 64);
        if (lane >= d) x += y;
    }
    __shared__ int wsum[4];
    if (lane == 63) wsum[w] = x;
    __syncthreads();
    int woff = 0;
    for (int i = 0; i < w; ++i) woff += wsum[i];
    int run = woff + x - tsum;
    #pragma unroll
    for (int i = 0; i < 4; ++i) {
        if (base + i < NN) offs[base + i] = run;
        run += v[i];
    }
    if (t == 255) csums[b] = woff + x;
}

__global__ void scan_tops_kernel(int* __restrict__ csums, int* __restrict__ offs, int nchunks) {
    if (threadIdx.x == 0 && blockIdx.x == 0) {
        int run = 0;
        for (int i = 0; i < nchunks; ++i) { int c = csums[i]; csums[i] = run; run += c; }
        offs[NN] = run;
    }
}

__global__ void scan_add_kernel(int* __restrict__ offs, const int* __restrict__ csums) {
    int i = blockIdx.x * blockDim.x + threadIdx.x;
    if (i < NN) offs[i] += csums[i >> 10];
}

// builds eperm (edge -> csr position), srcp and dstp (csr-ordered src/dst)
__global__ void scatter_kernel(const int* __restrict__ dst, const int* __restrict__ src,
                               const int* __restrict__ offs, int* __restrict__ cursor,
                               int* __restrict__ eperm, int* __restrict__ srcp,
                               int* __restrict__ dstp)
{
    int e = blockIdx.x * blockDim.x + threadIdx.x;
    if (e >= NE) return;
    int d = dst[e];
    int pos = offs[d] + atomicAdd(&cursor[d], 1);
    eperm[e] = pos;
    srcp[pos] = src[e];
    dstp[pos] = d;
}

__global__ void gstart_kernel(const int* __restrict__ batch, int* __restrict__ gstart) {
    int n = blockIdx.x * blockDim.x + threadIdx.x;
    if (n > NN) return;
    if (n == NN) {
        for (int g = batch[NN - 1] + 1; g <= NG; ++g) gstart[g] = NN;
        return;
    }
    int b = batch[n];
    int pb = (n == 0) ? -1 : batch[n - 1];
    for (int g = pb + 1; g <= b; ++g) gstart[g] = n;
}

// ---------------- conversions ----------------------------------------------

// ea f32 [E,101] -> bf16 [EP,128] in CSR order; col 101 = 1.0 (bias slot)
__global__ __launch_bounds__(256) void cvt_ea_kernel(const float* __restrict__ ea,
                                                     const int* __restrict__ eperm,
                                                     ushort* __restrict__ eabc)
{
    const int t = threadIdx.x;
    const int r = blockIdx.x * 8 + (t >> 5);
    if (r >= NE) return;
    const int pos = eperm[r];
    const int c = (t & 31) * 4;
    ushort4 o;
    #pragma unroll
    for (int i = 0; i < 4; ++i) {
        const int col = c + i;
        float v = (col < DE) ? ea[(size_t)r * DE + col] : ((col == DE) ? 1.0f : 0.0f);
        ((ushort*)&o)[i] = f2bf(v);
    }
    *(ushort4*)&eabc[(size_t)pos * 128 + c] = o;
}

// in f32 [Kin,Nn] -> out bf16 [Nn][Kp] transposed; row Kin = bias (if given), rest 0
__global__ void cvt_wt_kernel(const float* __restrict__ in, ushort* __restrict__ out,
                              int Kin, int Nn, int Kp, const float* __restrict__ bias)
{
    const int n = blockIdx.x;
    for (int k = threadIdx.x; k < Kp; k += blockDim.x) {
        float v = 0.0f;
        if (k < Kin) v = in[(size_t)k * Nn + n];
        else if (k == Kin && bias) v = bias[n];
        out[(size_t)n * Kp + k] = f2bf(v);
    }
}

// ---------------- fused edge GEMM + segment-sum aggregation ------------------
// e = eabc@We(+be via K-slot); val = relu(e + h[srcp]); zf[dst] += segment sums.
// Identical to the round-7 structure (174 us/layer) except the two barriers
// are LDS-only: no vmcnt(0) drain of the ~2700 per-tile zf atomics.
__global__ __launch_bounds__(256, 2) void edge_agg_kernel(
    const ushort* __restrict__ eab, const ushort* __restrict__ Wt,
    const int* __restrict__ srcp, const int* __restrict__ dstp,
    const ushort* __restrict__ hb, float* __restrict__ zf)
{
    __shared__ ushort vals[128 * 128];   // [row][col], col XOR-swizzled by row
    __shared__ int nd[128];              // dst node per tile row
    const int tid = threadIdx.x;
    const int wid = tid >> 6;
    const int msub = wid >> 1, nsl = wid & 1;
    const int lane = tid & 63, l15 = lane & 15, grp = lane >> 4;
    const int n0 = nsl * 64;

    bf16x8 A[4][4];
    #pragma unroll
    for (int nf = 0; nf < 4; ++nf)
        #pragma unroll
        for (int kk = 0; kk < 4; ++kk)
            A[nf][kk] = *(const bf16x8*)(Wt + (size_t)(n0 + nf * 16 + l15) * 128 + kk * 32 + grp * 8);

    const int rcol = tid & 127;   // reduce-phase column
    const int rh   = tid >> 7;    // reduce-phase row half (0/1)

    const int ntiles = EP / 128;  // 4688
    for (int t = blockIdx.x; t < ntiles; t += gridDim.x) {
        const int r0 = t * 128;
        const int m0 = r0 + msub * 64;
        BARRIER_LDS();            // previous tile's reduce done before overwriting LDS
        if (tid < 128) {
            const int rr = r0 + tid;
            nd[tid] = (rr < NE) ? dstp[rr] : NN;
        }
        // issue h-gather early (hides under MFMA)
        int sp[4];
        #pragma unroll
        for (int mf = 0; mf < 4; ++mf) {
            const int rr = m0 + mf * 16 + l15;
            sp[mf] = (rr < NE) ? srcp[rr] : 0;
        }
        ushort4 hv[4][4];
        #pragma unroll
        for (int mf = 0; mf < 4; ++mf)
            #pragma unroll
            for (int nf = 0; nf < 4; ++nf)
                hv[mf][nf] = *(const ushort4*)&hb[(size_t)sp[mf] * 128 + n0 + nf * 16 + grp * 4];
        // GEMM
        f32x4 acc[4][4];
        #pragma unroll
        for (int i = 0; i < 4; ++i)
            #pragma unroll
            for (int j = 0; j < 4; ++j) acc[i][j] = (f32x4){0.f, 0.f, 0.f, 0.f};
        #pragma unroll
        for (int kk = 0; kk < 4; ++kk) {
            bf16x8 b[4];
            #pragma unroll
            for (int mf = 0; mf < 4; ++mf)
                b[mf] = *(const bf16x8*)(eab + (size_t)(m0 + mf * 16 + l15) * 128 + kk * 32 + grp * 8);
            #pragma unroll
            for (int mf = 0; mf < 4; ++mf)
                #pragma unroll
                for (int nf = 0; nf < 4; ++nf)
                    acc[mf][nf] = __builtin_amdgcn_mfma_f32_16x16x32_bf16(A[nf][kk], b[mf], acc[mf][nf], 0, 0, 0);
        }
        // relu(e + h) -> LDS (swizzled: ushort-index col ^ ((row&7)<<3))
        #pragma unroll
        for (int mf = 0; mf < 4; ++mf) {
            const int row = msub * 64 + mf * 16 + l15;
            const int sw = (row & 7) << 3;
            #pragma unroll
            for (int nf = 0; nf < 4; ++nf) {
                const int col = n0 + nf * 16 + grp * 4;
                ushort4 o;
                o.x = f2bf(fmaxf(acc[mf][nf][0] + bf2f(hv[mf][nf].x), 0.f));
                o.y = f2bf(fmaxf(acc[mf][nf][1] + bf2f(hv[mf][nf].y), 0.f));
                o.z = f2bf(fmaxf(acc[mf][nf][2] + bf2f(hv[mf][nf].z), 0.f));
                o.w = f2bf(fmaxf(acc[mf][nf][3] + bf2f(hv[mf][nf].w), 0.f));
                *(ushort4*)&vals[row * 128 + (col ^ sw)] = o;
            }
        }
        BARRIER_LDS();
        // serial segment reduce down the tile (branches wave-uniform: rows shared)
        float accs = 0.f;
        int cur = nd[rh * 64];
        for (int r = rh * 64; r < rh * 64 + 64; ++r) {
            const int node = nd[r];
            const float v = bf2f(vals[r * 128 + (rcol ^ ((r & 7) << 3))]);
            if (node != cur) {
                if (cur < NN) fadd_atomic(&zf[(size_t)cur * 128 + rcol], accs);
                accs = 0.f; cur = node;
            }
            accs += v;
        }
        if (cur < NN) fadd_atomic(&zf[(size_t)cur * 128 + rcol], accs);
    }
}

// zf = f32(hb) for rows < NN, 0 for padded rows
__global__ void zinit_kernel(const ushort* __restrict__ hb, float* __restrict__ zf) {
    int i = blockIdx.x * blockDim.x + threadIdx.x;
    const int stride = gridDim.x * blockDim.x;
    for (; i < NP * 32; i += stride) {
        const int n = i >> 5;
        float4 o;
        if (n < NN) {
            ushort4 u = *(const ushort4*)&hb[(size_t)i * 4];
            o.x = bf2f(u.x); o.y = bf2f(u.y); o.z = bf2f(u.z); o.w = bf2f(u.w);
        } else {
            o.x = 0.f; o.y = 0.f; o.z = 0.f; o.w = 0.f;
        }
        *(float4*)&zf[(size_t)i * 4] = o;
    }
}

// ---------------- weight-stationary MFMA GEMMs ------------------------------

// mlp1: y1 = z@W1 + b1 -> bf16 [NP,256]; z is f32, converted in-register
__global__ __launch_bounds__(256, 2) void mlp1_gemm_kernel(
    const float* __restrict__ z, const ushort* __restrict__ Wt,
    const float* __restrict__ bias, ushort* __restrict__ y)
{
    const int n0 = (threadIdx.x >> 6) * 64;
    const int lane = threadIdx.x & 63, l15 = lane & 15, grp = lane >> 4;
    bf16x8 A[4][4];
    #pragma unroll
    for (int nf = 0; nf < 4; ++nf)
        #pragma unroll
        for (int kk = 0; kk < 4; ++kk)
            A[nf][kk] = *(const bf16x8*)(Wt + (size_t)(n0 + nf * 16 + l15) * 128 + kk * 32 + grp * 8);
    float4 bv[4];
    #pragma unroll
    for (int nf = 0; nf < 4; ++nf) bv[nf] = *(const float4*)&bias[n0 + nf * 16 + grp * 4];

    const int ntiles = NP / 64;   // 1564
    for (int t = blockIdx.x; t < ntiles; t += gridDim.x) {
        const int m0 = t * 64;
        f32x4 acc[4][4];
        #pragma unroll
        for (int i = 0; i < 4; ++i)
            #pragma unroll
            for (int j = 0; j < 4; ++j) acc[i][j] = (f32x4){0.f, 0.f, 0.f, 0.f};
        #pragma unroll
        for (int kk = 0; kk < 4; ++kk) {
            bf16x8 b[4];
            #pragma unroll
            for (int mf = 0; mf < 4; ++mf)
                b[mf] = ld_zfrag(z + (size_t)(m0 + mf * 16 + l15) * 128 + kk * 32 + grp * 8);
            #pragma unroll
            for (int mf = 0; mf < 4; ++mf)
                #pragma unroll
                for (int nf = 0; nf < 4; ++nf)
                    acc[mf][nf] = __builtin_amdgcn_mfma_f32_16x16x32_bf16(A[nf][kk], b[mf], acc[mf][nf], 0, 0, 0);
        }
        #pragma unroll
        for (int mf = 0; mf < 4; ++mf) {
            ushort* rp = &y[(size_t)(m0 + mf * 16 + l15) * 256 + n0];
            #pragma unroll
            for (int nf = 0; nf < 4; ++nf) {
                ushort4 o;
                o.x = f2bf(acc[mf][nf][0] + bv[nf].x);
                o.y = f2bf(acc[mf][nf][1] + bv[nf].y);
                o.z = f2bf(acc[mf][nf][2] + bv[nf].z);
                o.w = f2bf(acc[mf][nf][3] + bv[nf].w);
                *(ushort4*)&rp[nf * 16 + grp * 4] = o;
            }
        }
    }
}

// mlp2: y2 = y1r@W2 + b2 -> bf16 [NP,128]  (y1r pre-activated in place), K=256
__global__ __launch_bounds__(256, 2) void mlp2_gemm_kernel(
    const ushort* __restrict__ y1, const ushort* __restrict__ Wt,
    const float* __restrict__ bias, ushort* __restrict__ y2)
{
    const int wid = threadIdx.x >> 6;
    const int msub = wid >> 1, nsl = wid & 1;
    const int lane = threadIdx.x & 63, l15 = lane & 15, grp = lane >> 4;
    const int n0 = nsl * 64;
    bf16x8 A[4][8];
    #pragma unroll
    for (int nf = 0; nf < 4; ++nf)
        #pragma unroll
        for (int kk = 0; kk < 8; ++kk)
            A[nf][kk] = *(const bf16x8*)(Wt + (size_t)(n0 + nf * 16 + l15) * 256 + kk * 32 + grp * 8);
    float4 bv[4];
    #pragma unroll
    for (int nf = 0; nf < 4; ++nf) bv[nf] = *(const float4*)&bias[n0 + nf * 16 + grp * 4];

    const int ntiles = NP / 128;   // 782
    for (int t = blockIdx.x; t < ntiles; t += gridDim.x) {
        const int m0 = t * 128 + msub * 64;
        f32x4 acc[4][4];
        #pragma unroll
        for (int i = 0; i < 4; ++i)
            #pragma unroll
            for (int j = 0; j < 4; ++j) acc[i][j] = (f32x4){0.f, 0.f, 0.f, 0.f};
        #pragma unroll
        for (int kk = 0; kk < 8; ++kk) {
            bf16x8 b[4];
            #pragma unroll
            for (int mf = 0; mf < 4; ++mf)
                b[mf] = *(const bf16x8*)(y1 + (size_t)(m0 + mf * 16 + l15) * 256 + kk * 32 + grp * 8);
            #pragma unroll
            for (int mf = 0; mf < 4; ++mf)
                #pragma unroll
                for (int nf = 0; nf < 4; ++nf)
                    acc[mf][nf] = __builtin_amdgcn_mfma_f32_16x16x32_bf16(A[nf][kk], b[mf], acc[mf][nf], 0, 0, 0);
        }
        #pragma unroll
        for (int mf = 0; mf < 4; ++mf) {
            ushort* rp = &y2[(size_t)(m0 + mf * 16 + l15) * 128 + n0];
            #pragma unroll
            for (int nf = 0; nf < 4; ++nf) {
                ushort4 o;
                o.x = f2bf(acc[mf][nf][0] + bv[nf].x);
                o.y = f2bf(acc[mf][nf][1] + bv[nf].y);
                o.z = f2bf(acc[mf][nf][2] + bv[nf].z);
                o.w = f2bf(acc[mf][nf][3] + bv[nf].w);
                *(ushort4*)&rp[nf * 16 + grp * 4] = o;
            }
        }
    }
}

// ---------------- elementwise / stats kernels --------------------------------

// h = bf16(x @ W_emb + b_emb)  (runs once)
__global__ __launch_bounds__(128) void embed_kernel(
    const float* __restrict__ x, const float* __restrict__ W,
    const float* __restrict__ b, ushort* __restrict__ hb)
{
    __shared__ float xs[4][DIN];
    const int n0 = blockIdx.x * 4;
    const int d  = threadIdx.x;
    for (int idx = d; idx < 4 * DIN; idx += 128) {
        int r = idx / DIN, c = idx - r * DIN;
        xs[r][c] = x[(size_t)n0 * DIN + idx];
    }
    __syncthreads();
    float bb = b[d];
    float a0 = bb, a1 = bb, a2 = bb, a3 = bb;
    for (int k = 0; k < DIN; ++k) {
        float w = W[k * DD + d];
        a0 = fmaf(xs[0][k], w, a0);
        a1 = fmaf(xs[1][k], w, a1);
        a2 = fmaf(xs[2][k], w, a2);
        a3 = fmaf(xs[3][k], w, a3);
    }
    hb[(size_t)(n0 + 0) * DD + d] = f2bf(a0);
    hb[(size_t)(n0 + 1) * DD + d] = f2bf(a1);
    hb[(size_t)(n0 + 2) * DD + d] = f2bf(a2);
    hb[(size_t)(n0 + 3) * DD + d] = f2bf(a3);
}

// column sums/sumsq of bf16 [*,256], rows < NN
__global__ __launch_bounds__(256) void colstats256_kernel(
    const ushort* __restrict__ y, float* __restrict__ s, float* __restrict__ q)
{
    const int t = threadIdx.x;
    const int cs = (t & 63) * 4, rg = t >> 6;
    const int r0 = blockIdx.x * 256;
    float ps0 = 0, ps1 = 0, ps2 = 0, ps3 = 0, pq0 = 0, pq1 = 0, pq2 = 0, pq3 = 0;
    for (int i = rg; i < 256; i += 4) {
        const int r = r0 + i;
        if (r >= NN) break;
        ushort4 u = *(const ushort4*)&y[(size_t)r * 256 + cs];
        float f0 = bf2f(u.x), f1 = bf2f(u.y), f2v = bf2f(u.z), f3 = bf2f(u.w);
        ps0 += f0; pq0 += f0 * f0;
        ps1 += f1; pq1 += f1 * f1;
        ps2 += f2v; pq2 += f2v * f2v;
        ps3 += f3; pq3 += f3 * f3;
    }
    __shared__ float SS[4][256], SQ[4][256];
    SS[rg][cs + 0] = ps0; SS[rg][cs + 1] = ps1; SS[rg][cs + 2] = ps2; SS[rg][cs + 3] = ps3;
    SQ[rg][cs + 0] = pq0; SQ[rg][cs + 1] = pq1; SQ[rg][cs + 2] = pq2; SQ[rg][cs + 3] = pq3;
    __syncthreads();
    if (rg == 0) {
        #pragma unroll
        for (int j = 0; j < 4; ++j) {
            const int c = cs + j;
            fadd_atomic(&s[c], SS[0][c] + SS[1][c] + SS[2][c] + SS[3][c]);
            fadd_atomic(&q[c], SQ[0][c] + SQ[1][c] + SQ[2][c] + SQ[3][c]);
        }
    }
}

// column sums/sumsq of bf16 [*,128], rows < NN
__global__ __launch_bounds__(256) void colstats128b_kernel(
    const ushort* __restrict__ y, float* __restrict__ s, float* __restrict__ q)
{
    const int t = threadIdx.x;
    const int cs = (t & 31) * 4, rg = t >> 5;
    const int r0 = blockIdx.x * 256;
    float ps0 = 0, ps1 = 0, ps2 = 0, ps3 = 0, pq0 = 0, pq1 = 0, pq2 = 0, pq3 = 0;
    for (int i = rg; i < 256; i += 8) {
        const int r = r0 + i;
        if (r >= NN) break;
        ushort4 u = *(const ushort4*)&y[(size_t)r * 128 + cs];
        float f0 = bf2f(u.x), f1 = bf2f(u.y), f2v = bf2f(u.z), f3 = bf2f(u.w);
        ps0 += f0; pq0 += f0 * f0;
        ps1 += f1; pq1 += f1 * f1;
        ps2 += f2v; pq2 += f2v * f2v;
        ps3 += f3; pq3 += f3 * f3;
    }
    __shared__ float SS[8][128], SQ[8][128];
    SS[rg][cs + 0] = ps0; SS[rg][cs + 1] = ps1; SS[rg][cs + 2] = ps2; SS[rg][cs + 3] = ps3;
    SQ[rg][cs + 0] = pq0; SQ[rg][cs + 1] = pq1; SQ[rg][cs + 2] = pq2; SQ[rg][cs + 3] = pq3;
    __syncthreads();
    if (rg == 0) {
        #pragma unroll
        for (int j = 0; j < 4; ++j) {
            const int c = cs + j;
            float sv = 0, qv = 0;
            #pragma unroll
            for (int g = 0; g < 8; ++g) { sv += SS[g][c]; qv += SQ[g][c]; }
            fadd_atomic(&s[c], sv);
            fadd_atomic(&q[c], qv);
        }
    }
}

__global__ void finalize_kernel(const float* __restrict__ s, const float* __restrict__ sq,
                                const float* __restrict__ g, const float* __restrict__ bb,
                                float* __restrict__ a, float* __restrict__ c,
                                int dim, float invN)
{
    int d = blockIdx.x * blockDim.x + threadIdx.x;
    if (d >= dim) return;
    float m  = s[d] * invN;
    float v  = sq[d] * invN - m * m;
    float rs = rsqrtf(v + 1e-5f);
    float ai = g[d] * rs;
    a[d] = ai;
    c[d] = bb[d] - m * ai;
}

// y1 = bf16(relu(bn1(y1))) in place, rows < NN  (256 cols)
__global__ void bnrelu_bf_kernel(ushort* __restrict__ y, const float* __restrict__ a,
                                 const float* __restrict__ c)
{
    int i = blockIdx.x * blockDim.x + threadIdx.x;
    const int stride = gridDim.x * blockDim.x;
    for (; i < NN * 64; i += stride) {
        const int cb = (i & 63) * 4;
        ushort4 u = *(const ushort4*)&y[(size_t)i * 4];
        const float4 av = *(const float4*)&a[cb];
        const float4 cv = *(const float4*)&c[cb];
        ushort4 o;
        o.x = f2bf(fmaxf(fmaf(bf2f(u.x), av.x, cv.x), 0.f));
        o.y = f2bf(fmaxf(fmaf(bf2f(u.y), av.y, cv.y), 0.f));
        o.z = f2bf(fmaxf(fmaf(bf2f(u.z), av.z, cv.z), 0.f));
        o.w = f2bf(fmaxf(fmaf(bf2f(u.w), av.w, cv.w), 0.f));
        *(ushort4*)&y[(size_t)i * 4] = o;
    }
}

// h = bf16(relu(bn(y2))) in place (layer 0, 128 cols)
__global__ void bnrelu_hb_kernel(ushort* __restrict__ hb, const float* __restrict__ a,
                                 const float* __restrict__ c)
{
    int i = blockIdx.x * blockDim.x + threadIdx.x;
    const int stride = gridDim.x * blockDim.x;
    for (; i < NN * 32; i += stride) {
        const int cb = (i & 31) * 4;
        ushort4 u = *(const ushort4*)&hb[(size_t)i * 4];
        const float4 av = *(const float4*)&a[cb];
        const float4 cv = *(const float4*)&c[cb];
        ushort4 o;
        o.x = f2bf(fmaxf(fmaf(bf2f(u.x), av.x, cv.x), 0.f));
        o.y = f2bf(fmaxf(fmaf(bf2f(u.y), av.y, cv.y), 0.f));
        o.z = f2bf(fmaxf(fmaf(bf2f(u.z), av.z, cv.z), 0.f));
        o.w = f2bf(fmaxf(fmaf(bf2f(u.w), av.w, cv.w), 0.f));
        *(ushort4*)&hb[(size_t)i * 4] = o;
    }
}

// final: out[g] = bn(mean over node range of y2)  (one wave per graph)
__global__ __launch_bounds__(256) void pool_kernel(
    const ushort* __restrict__ hb, const float* __restrict__ a2, const float* __restrict__ c2,
    const int* __restrict__ gstart, float* __restrict__ out)
{
    const int g = blockIdx.x * 4 + (threadIdx.x >> 6);
    if (g >= NG) return;
    const int lane = threadIdx.x & 63;
    const int s = gstart[g], t = gstart[g + 1];
    float a0 = 0.f, a1 = 0.f;
    for (int n = s; n < t; ++n) {
        const uint v = *(const uint*)&hb[(size_t)n * 128 + lane * 2];
        a0 += __uint_as_float(v << 16);
        a1 += __uint_as_float(v & 0xffff0000u);
    }
    const int d0 = lane * 2;
    float2 o;
    if (t > s) {
        const float inv = 1.0f / (float)(t - s);
        o.x = fmaf(a2[d0 + 0], a0 * inv, c2[d0 + 0]);
        o.y = fmaf(a2[d0 + 1], a1 * inv, c2[d0 + 1]);
    } else {
        o.x = 0.f; o.y = 0.f;
    }
    *(float2*)&out[(size_t)g * 128 + d0] = o;
}

// ---------------- launch ----------------------------------------------------

extern "C" void kernel_launch(void* const* d_in, const int* in_sizes, int n_in,
                              void* d_out, int out_size, void* d_ws, size_t ws_size,
                              hipStream_t stream)
{
    (void)in_sizes; (void)n_in; (void)out_size; (void)ws_size;
    const float* x     = (const float*)d_in[0];
    const float* ea    = (const float*)d_in[1];
    const int*   src   = (const int*)d_in[2];
    const int*   dst   = (const int*)d_in[3];
    const int*   batch = (const int*)d_in[4];
    const float* W_emb = (const float*)d_in[5];
    const float* b_emb = (const float*)d_in[6];

    char* ws = (char*)d_ws;
    auto alloc = [&](size_t bytes) { void* p = ws; ws += (bytes + 255) & ~(size_t)255; return p; };

    ushort* hb   = (ushort*)alloc((size_t)NP * 128 * 2);   // 25.6 MB  h / y2 (bf16)
    float*  zf   = (float*) alloc((size_t)NP * 128 * 4);   // 51.2 MB  z (f32)
    ushort* eabc = (ushort*)alloc((size_t)EP * 128 * 2);   // 153.6 MB ea bf16, CSR order
    ushort* y1b  = (ushort*)alloc((size_t)NP * 256 * 2);   // 51.2 MB  y1 (bf16)
    int* deg    = (int*)alloc((size_t)NN * 4);
    int* offs   = (int*)alloc((size_t)(NN + 1) * 4);
    int* eperm  = (int*)alloc((size_t)NE * 4);
    int* srcp   = (int*)alloc((size_t)NE * 4);
    int* dstp   = (int*)alloc((size_t)NE * 4);
    int* csums  = (int*)alloc(128 * 4);
    int* gstart = (int*)alloc((size_t)(NG + 1) * 4);
    ushort* Wet[2], *W1t[2], *W2t[2];
    for (int l = 0; l < 2; ++l) {
        Wet[l] = (ushort*)alloc(128 * 128 * 2);
        W1t[l] = (ushort*)alloc(256 * 128 * 2);
        W2t[l] = (ushort*)alloc(128 * 256 * 2);
    }
    float* st = (float*)alloc(2048 * 4);
    float* s1 = st,        *sq1 = st + 256, *a1 = st + 512,  *c1 = st + 768;
    float* s2 = st + 1024, *sq2 = st + 1152, *a2 = st + 1280, *c2 = st + 1408;
    float* out = (float*)d_out;

    const int NCHUNK = (NN + 1023) / 1024;

    // CSR + permutation + graph boundaries (constant across layers)
    hipMemsetAsync(deg, 0, (size_t)NN * 4, stream);
    hist_kernel<<<(NE + 255) / 256, 256, 0, stream>>>(dst, deg);
    scan_chunk_kernel<<<NCHUNK, 256, 0, stream>>>(deg, offs, csums);
    scan_tops_kernel<<<1, 1, 0, stream>>>(csums, offs, NCHUNK);
    scan_add_kernel<<<(NN + 255) / 256, 256, 0, stream>>>(offs, csums);
    hipMemsetAsync(deg, 0, (size_t)NN * 4, stream);
    scatter_kernel<<<(NE + 255) / 256, 256, 0, stream>>>(dst, src, offs, deg, eperm, srcp, dstp);
    gstart_kernel<<<(NN + 256) / 256, 256, 0, stream>>>(batch, gstart);

    // one-time conversions (ea goes directly to CSR order, bias slot at col 101)
    cvt_ea_kernel<<<(NE + 7) / 8, 256, 0, stream>>>(ea, eperm, eabc);
    for (int l = 0; l < 2; ++l) {
        const float* const* L = (const float* const*)(d_in + 7 + l * 10);
        cvt_wt_kernel<<<128, 128, 0, stream>>>(L[0], Wet[l], 101, 128, 128, L[1]);  // We + be row
        cvt_wt_kernel<<<256, 128, 0, stream>>>(L[2], W1t[l], 128, 256, 128, nullptr);
        cvt_wt_kernel<<<128, 128, 0, stream>>>(L[6], W2t[l], 256, 128, 256, nullptr);
    }

    embed_kernel<<<NN / 4, 128, 0, stream>>>(x, W_emb, b_emb, hb);

    for (int layer = 0; layer < 2; ++layer) {
        const float* const* L = (const float* const*)(d_in + 7 + layer * 10);
        const float* b1  = L[3];
        const float* g1  = L[4]; const float* bb1 = L[5];
        const float* b2  = L[7];
        const float* go  = L[8]; const float* bo  = L[9];

        zinit_kernel<<<2048, 256, 0, stream>>>(hb, zf);
        edge_agg_kernel<<<1172, 256, 0, stream>>>(eabc, Wet[layer], srcp, dstp, hb, zf);

        hipMemsetAsync(s1, 0, 512 * sizeof(float), stream);
        hipMemsetAsync(s2, 0, 256 * sizeof(float), stream);

        mlp1_gemm_kernel<<<782, 256, 0, stream>>>(zf, W1t[layer], b1, y1b);
        colstats256_kernel<<<NP / 256 + 1, 256, 0, stream>>>(y1b, s1, sq1);
        finalize_kernel<<<1, 256, 0, stream>>>(s1, sq1, g1, bb1, a1, c1, 256, 1.0f / NN);
        bnrelu_bf_kernel<<<2048, 256, 0, stream>>>(y1b, a1, c1);
        mlp2_gemm_kernel<<<391, 256, 0, stream>>>(y1b, W2t[layer], b2, hb);
        colstats128b_kernel<<<NP / 256 + 1, 256, 0, stream>>>(hb, s2, sq2);
        finalize_kernel<<<1, 128, 0, stream>>>(s2, sq2, go, bo, a2, c2, 128, 1.0f / NN);

        if (layer == 0) {
            bnrelu_hb_kernel<<<2048, 256, 0, stream>>>(hb, a2, c2);
        } else {
            pool_kernel<<<NG / 4, 256, 0, stream>>>(hb, a2, c2, gstart, out);
        }
    }
}